// Round 14
// baseline (299.237 us; speedup 1.0000x reference)
//
#include <hip/hip_runtime.h>
#include <stdint.h>

// HyperLatticeBlock: B=2,S=1024,D=1024,L=48,K=4  (tokens T=2048)
// prep(gate+wconvT fused) -> expert GEMM (ZERO-sync, reg-only, per-wave 64x64) -> combine -> out_proj -> LN
#define TT 2048
#define DD 1024
#define LL 48
#define SENT (LL * 256)   // sentinel selp row (zeroed)

typedef __attribute__((ext_vector_type(8))) short short8;
typedef __attribute__((ext_vector_type(4))) float f32x4;

static __device__ __forceinline__ unsigned int f2bf(float f) {
  union { float f; unsigned int u; } v; v.f = f;
  return (v.u + 0x7FFFu + ((v.u >> 16) & 1u)) >> 16;   // RNE f32->bf16 bits
}
static __device__ __forceinline__ unsigned int pack2(float a, float b) {
  return f2bf(a) | (f2bf(b) << 16);
}

// ---------------- prep: gate (blocks 0..255) + wconvT (blocks 256..3327), co-scheduled ------------
__global__ __launch_bounds__(256) void k_prep(
    const float* __restrict__ x, const float* __restrict__ gw, const float* __restrict__ W,
    unsigned short* __restrict__ xg, unsigned short* __restrict__ Wt,
    int* __restrict__ counts, float* __restrict__ bscore, int* __restrict__ tpos)
{
  __shared__ union {
    struct { float xs[8][1024]; float lg[8][48]; int tp_s[32]; } g;
    unsigned short T[128][136];
  } sm;
  const int tid = threadIdx.x;

  if (blockIdx.x < 256) {
    // ================= gate =================
    const int t0 = blockIdx.x * 8;
    for (int u = tid; u < 2048; u += 256) {
      int tok = u >> 8;
      int c = (u & 255) << 2;
      float4 v = *(const float4*)(x + (size_t)(t0 + tok) * DD + c);
      *(float4*)&sm.g.xs[tok][c] = v;
    }
    __syncthreads();
    const int lane = tid & 63, wid = tid >> 6;
    for (int li = 0; li < 12; ++li) {
      const int l = wid + (li << 2);
      const float4* gp = (const float4*)(gw + (size_t)l * DD);
      float4 g0 = gp[lane], g1 = gp[lane + 64], g2 = gp[lane + 128], g3 = gp[lane + 192];
      for (int tok = 0; tok < 8; ++tok) {
        const float4* xp = (const float4*)&sm.g.xs[tok][0];
        float4 a0 = xp[lane], a1 = xp[lane + 64], a2 = xp[lane + 128], a3 = xp[lane + 192];
        float s = a0.x*g0.x + a0.y*g0.y + a0.z*g0.z + a0.w*g0.w
                + a1.x*g1.x + a1.y*g1.y + a1.z*g1.z + a1.w*g1.w
                + a2.x*g2.x + a2.y*g2.y + a2.z*g2.z + a2.w*g2.w
                + a3.x*g3.x + a3.y*g3.y + a3.z*g3.z + a3.w*g3.w;
        #pragma unroll
        for (int off = 32; off; off >>= 1) s += __shfl_down(s, off);
        if (lane == 0) sm.g.lg[tok][l] = s;
      }
    }
    __syncthreads();
    if (tid < 8) {
      const int tok = tid;
      float v[4]; int id[4];
      unsigned long long taken = 0ull;
      for (int k = 0; k < 4; ++k) {
        float best = -3.4e38f; int bi = 0;
        for (int l = 0; l < 48; ++l) {
          float cand = sm.g.lg[tok][l];
          if (!((taken >> l) & 1ull) && cand > best) { best = cand; bi = l; }
        }
        taken |= (1ull << bi); v[k] = best; id[k] = bi;
      }
      float e1 = expf(v[1] - v[0]);
      float e2 = expf(v[2] - v[0]);
      float e3 = expf(v[3] - v[0]);
      float inv = 1.0f / (1.0f + e1 + e2 + e3);
      float sc[4] = { inv, e1*inv, e2*inv, e3*inv };
      for (int k = 0; k < 4; ++k) {
        int pos = atomicAdd(&counts[id[k]], 1);
        bscore[id[k] * TT + pos] = sc[k];
        int dst = (pos < 256) ? (id[k] * 256 + pos) : SENT;
        sm.g.tp_s[tok * 4 + k] = dst;
        tpos[((t0 + tok) << 2) | k] = dst;
      }
    }
    __syncthreads();
    for (int g = 0; g < 32; ++g) {
      int dst = sm.g.tp_s[g];
      if (dst == SENT) continue;
      const float* src = sm.g.xs[g >> 2];
      float a0 = src[tid * 4], a1 = src[tid * 4 + 1], a2 = src[tid * 4 + 2], a3 = src[tid * 4 + 3];
      uint2 pk; pk.x = pack2(a0, a1); pk.y = pack2(a2, a3);
      *(uint2*)(xg + (size_t)dst * DD + tid * 4) = pk;
    }
  } else {
    // ================= wconvT: Wt[l][e][d] bf16 <- W[l][d][e] f32 (r3/r13-verified body) =========
    const int b2 = blockIdx.x - 256;
    const int l = b2 >> 6, d0 = ((b2 >> 3) & 7) * 128, e0 = (b2 & 7) * 128;
    const float* src = W + (size_t)l * DD * DD;
    #pragma unroll
    for (int i = 0; i < 16; ++i) {
      int fl = i * 256 + tid;
      int d = fl >> 5, e4 = fl & 31;
      float4 v = *(const float4*)(src + (size_t)(d0 + d) * DD + e0 + e4 * 4);
      #pragma unroll
      for (int j = 0; j < 4; ++j) {
        int e = e4 * 4 + j;
        int unit = (d >> 3) ^ (e & 7);
        float fv = (j == 0) ? v.x : (j == 1) ? v.y : (j == 2) ? v.z : v.w;
        sm.T[e][unit * 8 + (d & 7)] = (unsigned short)f2bf(fv);
      }
    }
    __syncthreads();
    #pragma unroll
    for (int i2 = 0; i2 < 8; ++i2) {
      int uo = i2 * 256 + tid;
      int e = uo >> 4, ds = uo & 15;
      short8 s8 = *(const short8*)&sm.T[e][(ds ^ (e & 7)) * 8];
      *(short8*)(Wt + ((size_t)l << 20) + (size_t)(e0 + e) * DD + d0 + ds * 8) = s8;
    }
  }
}

// ---------------- expert GEMM: ZERO-sync. Per wave: independent 64x64 tile, BK=64 reg-dbuf ------
// No LDS, no barriers, no asm waits -- compiler emits count-precise vmcnt per register dep.
// grid 768: bid = nq*48 + l  (an expert's 16 n-tiles share an XCD since 48%8==0).
__global__ __launch_bounds__(256, 2) void k_expert(
    const unsigned short* __restrict__ xg, const unsigned short* __restrict__ Wt,
    const int* __restrict__ counts, const float* __restrict__ bscore,
    float* __restrict__ selp)
{
  const int bid = blockIdx.x;
  const int l = bid % LL;
  const int n0 = (bid / LL) * 64;
  const int ncnt = min(counts[l], 256);
  const int tid = threadIdx.x, lane = tid & 63, w = tid >> 6;
  const int fr = lane & 15, fq = lane >> 4;
  const int mbase = w * 64;
  if (mbase >= ncnt) return;   // whole wave idle (no barriers in kernel -> safe)

  const unsigned short* ap[4];
  const unsigned short* bp[4];
  #pragma unroll
  for (int m = 0; m < 4; ++m)
    ap[m] = xg + ((size_t)(l * 256 + mbase + m * 16 + fr) << 10) + fq * 8;
  #pragma unroll
  for (int n = 0; n < 4; ++n)
    bp[n] = Wt + ((size_t)l << 20) + ((size_t)(n0 + n * 16 + fr) << 10) + fq * 8;

  f32x4 acc[4][4];
  #pragma unroll
  for (int m = 0; m < 4; ++m)
    #pragma unroll
    for (int n = 0; n < 4; ++n)
      #pragma unroll
      for (int j = 0; j < 4; ++j) acc[m][n][j] = 0.f;

  short8 aA[4][2], bA[4][2], aB[4][2], bB[4][2];   // static-indexed reg double buffer

#define E_LD(DA, DB, t) do { \
    _Pragma("unroll") for (int m = 0; m < 4; ++m) { \
      DA[m][0] = *(const short8*)(ap[m] + (t) * 64); \
      DA[m][1] = *(const short8*)(ap[m] + (t) * 64 + 32); } \
    _Pragma("unroll") for (int n = 0; n < 4; ++n) { \
      DB[n][0] = *(const short8*)(bp[n] + (t) * 64); \
      DB[n][1] = *(const short8*)(bp[n] + (t) * 64 + 32); } } while (0)

#define E_CP(SA, SB) do { \
    _Pragma("unroll") for (int m = 0; m < 4; ++m) \
      _Pragma("unroll") for (int n = 0; n < 4; ++n) \
        acc[m][n] = __builtin_amdgcn_mfma_f32_16x16x32_bf16(SA[m][0], SB[n][0], acc[m][n], 0, 0, 0); \
    _Pragma("unroll") for (int m = 0; m < 4; ++m) \
      _Pragma("unroll") for (int n = 0; n < 4; ++n) \
        acc[m][n] = __builtin_amdgcn_mfma_f32_16x16x32_bf16(SA[m][1], SB[n][1], acc[m][n], 0, 0, 0); } while (0)

  E_LD(aA, bA, 0);
  #pragma unroll 1
  for (int tt = 0; tt < 16; tt += 2) {
    E_LD(aB, bB, tt + 1);
    E_CP(aA, bA);
    if (tt + 2 < 16) E_LD(aA, bA, tt + 2);
    E_CP(aB, bB);
  }
#undef E_LD
#undef E_CP

  // epilogue: D[r][c]: c = lane&15 (e), r = (lane>>4)*4 + j  [m89-verified]
  #pragma unroll
  for (int m = 0; m < 4; ++m) {
    #pragma unroll
    for (int j = 0; j < 4; ++j) {
      const int r = mbase + m * 16 + fq * 4 + j;
      if (r < ncnt) {
        const float sc = bscore[l * TT + r];
        float* op = selp + ((size_t)(l * 256 + r) << 10) + n0 + fr;
        #pragma unroll
        for (int n = 0; n < 4; ++n) op[n * 16] = acc[m][n][j] * sc;
      }
    }
  }
}

// ---------------- combine: lat_bf16[t][d] = sum_k selp[tpos[t*4+k]][d] ----------------
__global__ __launch_bounds__(256) void k_combine(const float* __restrict__ selp,
    const int* __restrict__ tpos, unsigned short* __restrict__ lat)
{
  const size_t i = ((size_t)blockIdx.x * 256 + threadIdx.x) << 2;
  const size_t t = i >> 10, d = i & 1023;
  int4 tp = *(const int4*)(tpos + (t << 2));
  float4 s0 = *(const float4*)(selp + (size_t)tp.x * DD + d);
  float4 s1 = *(const float4*)(selp + (size_t)tp.y * DD + d);
  float4 s2 = *(const float4*)(selp + (size_t)tp.z * DD + d);
  float4 s3 = *(const float4*)(selp + (size_t)tp.w * DD + d);
  float r0 = s0.x + s1.x + s2.x + s3.x;
  float r1 = s0.y + s1.y + s2.y + s3.y;
  float r2 = s0.z + s1.z + s2.z + s3.z;
  float r3 = s0.w + s1.w + s2.w + s3.w;
  uint2 pk; pk.x = pack2(r0, r1); pk.y = pack2(r2, r3);
  *(uint2*)(lat + i) = pk;
}

// ---------------- out_proj: y = x + lat @ out_w^T + b  (BM=128,BN=64, reg-staged dbuf) ----------------
__global__ __launch_bounds__(256, 2) void k_outproj(
    const unsigned short* __restrict__ lat, const float* __restrict__ W2,
    const float* __restrict__ xres, const float* __restrict__ bias,
    float* __restrict__ y)
{
  const int n0 = blockIdx.x * 64;
  const int m0 = blockIdx.y * 128;
  const int tid = threadIdx.x, lane = tid & 63, wid = tid >> 6;

  __shared__ alignas(16) unsigned short As[2][128][40];
  __shared__ alignas(16) unsigned short Bs[2][64][40];

  const int aq = tid >> 2, aseg = tid & 3;
  const unsigned short* la0 = lat + (size_t)(m0 + aq) * DD + aseg * 8;
  const unsigned short* la1 = lat + (size_t)(m0 + aq + 64) * DD + aseg * 8;
  const int be = tid >> 2, bks = tid & 3;
  const float* wb = W2 + (size_t)(n0 + be) * DD + bks * 8;

  f32x4 acc[2][4];
  #pragma unroll
  for (int m = 0; m < 2; ++m)
    #pragma unroll
    for (int n = 0; n < 4; ++n)
      #pragma unroll
      for (int j = 0; j < 4; ++j) acc[m][n][j] = 0.f;

  int4 av0, av1;
  float4 w0, w1;

#define O_LOAD(kk) do { \
    av0 = *(const int4*)(la0 + (kk)); \
    av1 = *(const int4*)(la1 + (kk)); \
    w0 = *(const float4*)(wb + (kk)); \
    w1 = *(const float4*)(wb + (kk) + 4); \
  } while (0)

#define O_STORE(b) do { \
    *(int4*)&As[b][aq][aseg * 8]      = av0; \
    *(int4*)&As[b][aq + 64][aseg * 8] = av1; \
    uint4 pv; \
    pv.x = pack2(w0.x, w0.y); pv.y = pack2(w0.z, w0.w); \
    pv.z = pack2(w1.x, w1.y); pv.w = pack2(w1.z, w1.w); \
    *(uint4*)&Bs[b][be][bks * 8] = pv; \
  } while (0)

  O_LOAD(0); O_STORE(0); __syncthreads();
  int cur = 0;
  for (int t = 0; t < 32; ++t) {
    const bool more = (t < 31);
    if (more) O_LOAD((t + 1) * 32);
    short8 af[2], bf[4];
    #pragma unroll
    for (int n = 0; n < 4; ++n)
      bf[n] = *(const short8*)&Bs[cur][n * 16 + (lane & 15)][(lane >> 4) * 8];
    #pragma unroll
    for (int m = 0; m < 2; ++m)
      af[m] = *(const short8*)&As[cur][wid * 32 + m * 16 + (lane & 15)][(lane >> 4) * 8];
    #pragma unroll
    for (int m = 0; m < 2; ++m)
      #pragma unroll
      for (int n = 0; n < 4; ++n)
        acc[m][n] = __builtin_amdgcn_mfma_f32_16x16x32_bf16(af[m], bf[n], acc[m][n], 0, 0, 0);
    if (more) O_STORE(cur ^ 1);
    __syncthreads();
    cur ^= 1;
  }
#undef O_LOAD
#undef O_STORE

  #pragma unroll
  for (int m = 0; m < 2; ++m) {
    #pragma unroll
    for (int j = 0; j < 4; ++j) {
      const int t = m0 + wid * 32 + m * 16 + ((lane >> 4) << 2) + j;
      #pragma unroll
      for (int n = 0; n < 4; ++n) {
        const int e = n0 + n * 16 + (lane & 15);
        y[(size_t)t * DD + e] = xres[(size_t)t * DD + e] + acc[m][n][j] + bias[e];
      }
    }
  }
}

// ---------------- LayerNorm ----------------
__global__ __launch_bounds__(256) void k_ln(const float* __restrict__ y,
    const float* __restrict__ g, const float* __restrict__ b, float* __restrict__ out)
{
  const int t = blockIdx.x, tid = threadIdx.x;
  float4 v = *(const float4*)(y + (size_t)t * DD + tid * 4);
  float s  = v.x + v.y + v.z + v.w;
  float ss = v.x*v.x + v.y*v.y + v.z*v.z + v.w*v.w;
  #pragma unroll
  for (int off = 32; off; off >>= 1) { s += __shfl_down(s, off); ss += __shfl_down(ss, off); }
  __shared__ float rs[8];
  const int wid = tid >> 6, lane = tid & 63;
  if (lane == 0) { rs[wid] = s; rs[wid + 4] = ss; }
  __syncthreads();
  float S  = rs[0] + rs[1] + rs[2] + rs[3];
  float SS = rs[4] + rs[5] + rs[6] + rs[7];
  float mu = S * (1.0f / DD);
  float var = SS * (1.0f / DD) - mu * mu;
  float inv = rsqrtf(var + 1e-5f);
  float4 gg = *(const float4*)(g + tid * 4);
  float4 bb = *(const float4*)(b + tid * 4);
  float4 o;
  o.x = gg.x * (v.x - mu) * inv + bb.x;
  o.y = gg.y * (v.y - mu) * inv + bb.y;
  o.z = gg.z * (v.z - mu) * inv + bb.z;
  o.w = gg.w * (v.w - mu) * inv + bb.w;
  *(float4*)(out + (size_t)t * DD + tid * 4) = o;
}

extern "C" void kernel_launch(void* const* d_in, const int* in_sizes, int n_in,
                              void* d_out, int out_size, void* d_ws, size_t ws_size,
                              hipStream_t stream) {
  (void)in_sizes; (void)n_in; (void)out_size;
  const float* x   = (const float*)d_in[0];
  const float* gw  = (const float*)d_in[1];
  const float* lw  = (const float*)d_in[2];
  const float* ow  = (const float*)d_in[3];
  const float* obv = (const float*)d_in[4];
  const float* lng = (const float*)d_in[5];
  const float* lnb = (const float*)d_in[6];
  float* out = (float*)d_out;
  char* ws = (char*)d_ws;

  // layout: xg 24MB @0 | selp 48MB+4K @24M | lat @73M | y @77M | counts @85M | bscore | tpos @86M
  //         Wt 96MB @96M..192M
  unsigned short* xg     = (unsigned short*)(ws);
  float*          selp   = (float*)(ws + (24ull << 20));
  unsigned short* lat    = (unsigned short*)(ws + (73ull << 20));
  float*          y      = (float*)(ws + (77ull << 20));
  int*            counts = (int*)(ws + (85ull << 20));
  float*          bscore = (float*)(ws + (85ull << 20) + 4096);
  int*            tpos   = (int*)(ws + (86ull << 20));
  unsigned short* Wt     = (unsigned short*)(ws + (96ull << 20));
  if (ws_size < (193ull << 20)) return;   // loud failure

  hipMemsetAsync(counts, 0, LL * sizeof(int), stream);
  hipMemsetAsync(selp + (size_t)SENT * DD, 0, DD * sizeof(float), stream);  // sentinel row
  k_prep<<<3328, 256, 0, stream>>>(x, gw, lw, xg, Wt, counts, bscore, tpos);
  k_expert<<<768, 256, 0, stream>>>(xg, Wt, counts, bscore, selp);
  k_combine<<<TT * DD / (256 * 4), 256, 0, stream>>>(selp, tpos, lat);
  k_outproj<<<dim3(16, 16), 256, 0, stream>>>(lat, ow, x, obv, y);
  k_ln<<<TT, 256, 0, stream>>>(y, lng, lnb, out);
}

// Round 15
// 186.057 us; speedup vs baseline: 1.6083x; 1.6083x over previous
//
#include <hip/hip_runtime.h>
#include <stdint.h>

// HyperLatticeBlock: B=2,S=1024,D=1024,L=48,K=4  (tokens T=2048)
// gate(top4+pack) -> expert GEMM (high-occupancy, 1-barrier/K-step counted pipeline)
//   -> combine -> out_proj -> LN
#define TT 2048
#define DD 1024
#define LL 48
#define SENT (LL * 256)   // sentinel selp row (zeroed)

typedef __attribute__((ext_vector_type(8))) short short8;
typedef __attribute__((ext_vector_type(4))) float f32x4;

static __device__ __forceinline__ unsigned int f2bf(float f) {
  union { float f; unsigned int u; } v; v.f = f;
  return (v.u + 0x7FFFu + ((v.u >> 16) & 1u)) >> 16;   // RNE f32->bf16 bits
}
static __device__ __forceinline__ unsigned int pack2(float a, float b) {
  return f2bf(a) | (f2bf(b) << 16);
}

typedef __attribute__((address_space(1))) const void* as1_t;
typedef __attribute__((address_space(3))) void* as3_t;
static __device__ __forceinline__ void gll16(const void* g, void* s) {
  __builtin_amdgcn_global_load_lds((as1_t)g, (as3_t)s, 16, 0, 0);
}

#define LGKM0 do { asm volatile("s_waitcnt lgkmcnt(0)" ::: "memory"); \
                   __builtin_amdgcn_sched_barrier(0); } while (0)
#define BARR  do { __builtin_amdgcn_s_barrier(); __builtin_amdgcn_sched_barrier(0); } while (0)

// ---------------- gate: logits fp32, top-4, softmax, bucket scatter + A-pack (r10-verified) ------
__global__ __launch_bounds__(256) void k_gate(
    const float* __restrict__ x, const float* __restrict__ gw,
    unsigned short* __restrict__ xg, int* __restrict__ counts,
    float* __restrict__ bscore, int* __restrict__ tpos)
{
  __shared__ float xs[8][1024];
  __shared__ float lg[8][48];
  __shared__ int tp_s[32];
  const int tid = threadIdx.x;
  const int t0 = blockIdx.x * 8;
  for (int u = tid; u < 2048; u += 256) {
    int tok = u >> 8;
    int c = (u & 255) << 2;
    float4 v = *(const float4*)(x + (size_t)(t0 + tok) * DD + c);
    *(float4*)&xs[tok][c] = v;
  }
  __syncthreads();
  const int lane = tid & 63, wid = tid >> 6;
  for (int li = 0; li < 12; ++li) {
    const int l = wid + (li << 2);
    const float4* gp = (const float4*)(gw + (size_t)l * DD);
    float4 g0 = gp[lane], g1 = gp[lane + 64], g2 = gp[lane + 128], g3 = gp[lane + 192];
    for (int tok = 0; tok < 8; ++tok) {
      const float4* xp = (const float4*)&xs[tok][0];
      float4 a0 = xp[lane], a1 = xp[lane + 64], a2 = xp[lane + 128], a3 = xp[lane + 192];
      float s = a0.x*g0.x + a0.y*g0.y + a0.z*g0.z + a0.w*g0.w
              + a1.x*g1.x + a1.y*g1.y + a1.z*g1.z + a1.w*g1.w
              + a2.x*g2.x + a2.y*g2.y + a2.z*g2.z + a2.w*g2.w
              + a3.x*g3.x + a3.y*g3.y + a3.z*g3.z + a3.w*g3.w;
      #pragma unroll
      for (int off = 32; off; off >>= 1) s += __shfl_down(s, off);
      if (lane == 0) lg[tok][l] = s;
    }
  }
  __syncthreads();
  if (tid < 8) {
    const int tok = tid;
    float v[4]; int id[4];
    unsigned long long taken = 0ull;
    for (int k = 0; k < 4; ++k) {
      float best = -3.4e38f; int bi = 0;
      for (int l = 0; l < 48; ++l) {
        float cand = lg[tok][l];
        if (!((taken >> l) & 1ull) && cand > best) { best = cand; bi = l; }
      }
      taken |= (1ull << bi); v[k] = best; id[k] = bi;
    }
    float e1 = expf(v[1] - v[0]);
    float e2 = expf(v[2] - v[0]);
    float e3 = expf(v[3] - v[0]);
    float inv = 1.0f / (1.0f + e1 + e2 + e3);
    float sc[4] = { inv, e1*inv, e2*inv, e3*inv };
    for (int k = 0; k < 4; ++k) {
      int pos = atomicAdd(&counts[id[k]], 1);
      bscore[id[k] * TT + pos] = sc[k];
      int dst = (pos < 256) ? (id[k] * 256 + pos) : SENT;
      tp_s[tok * 4 + k] = dst;
      tpos[((t0 + tok) << 2) | k] = dst;
    }
  }
  __syncthreads();
  for (int g = 0; g < 32; ++g) {
    int dst = tp_s[g];
    if (dst == SENT) continue;
    const float* src = xs[g >> 2];
    float a0 = src[tid * 4], a1 = src[tid * 4 + 1], a2 = src[tid * 4 + 2], a3 = src[tid * 4 + 3];
    uint2 pk; pk.x = pack2(a0, a1); pk.y = pack2(a2, a3);
    *(uint2*)(xg + (size_t)dst * DD + tid * 4) = pk;
  }
}

// ---------------- expert GEMM: BM=128, BN=64, BK=32, 256 thr (2m x 2n waves, 64x32 tiles) --------
// High-occupancy: grid 1536 (=6/CU avail), __launch_bounds__(256,4) -> 4 blocks/CU = 16 waves/CU.
// Per K-step: G(t+2)[2 vmem] ; vmcnt(2) ; lgkm(0) ; s_barrier ; gll_A(t+1) ; BSTORE B(t+1) ;
//             COMPUTE(t).  Counted waits -- drains only in 2 peeled tail iterations.
// A LDS [128][32] with 4-slot XOR swizzle (pre-swizzled global source); B fp32 coalesced ->
// bf16 pack -> LDS [16][68] (read conflict-free).
__global__ __launch_bounds__(256, 4) void k_expert(
    const unsigned short* __restrict__ xg, const float* __restrict__ W,
    const int* __restrict__ counts, const float* __restrict__ bscore,
    float* __restrict__ selp)
{
  const int bid = blockIdx.x;
  const int l = bid % LL;                  // all 32 tiles of expert l on one XCD (48%8==0)
  const int tcode = bid / LL;              // 0..31
  const int mh = tcode & 1;                // m-half: rows mh*128..mh*128+127
  const int n0 = (tcode >> 1) * 64;        // 16 n-tiles
  const int ncnt = min(counts[l], 256);
  if (mh * 128 >= ncnt) return;
  const int tid = threadIdx.x, lane = tid & 63, wid = tid >> 6;
  const int mw = wid >> 1, nw = wid & 1;   // wave tile: rows mw*64+, cols nw*32+
  const int fr = lane & 15, fq = lane >> 4;

  __shared__ unsigned short As[2][128][32];   // 16 KB (64B rows)
  __shared__ unsigned int   Bs[2][16 * 68];   // 8.7 KB

  // A staging: 2 gll16/thread: unit u=i*256+tid -> row i*64+(tid>>2), phys slot tid&3.
  // dest offset is 16B*lane-linear (verified); source pre-swizzled: logical slot = (tid&3)^((tid>>2)&3).
  const int arow = tid >> 2;
  const int aslot = (tid & 3) ^ ((tid >> 2) & 3);
  const unsigned short* ax0 = xg + ((size_t)(l * 256 + mh * 128 + arow) << 10) + aslot * 8;
  const unsigned short* ax1 = ax0 + ((size_t)64 << 10);
  // B staging: thread -> d-pair bp=tid>>4 (0..15), 4 e's at (tid&15)*4 (coalesced fp32 loads)
  const int bp = tid >> 4, be = (tid & 15) << 2;
  const float* wsrc0 = W + (size_t)l * DD * DD + (size_t)(bp << 1) * DD + n0 + be;
  const float* wsrc1 = wsrc0 + DD;

  // frag-read addresses (loop-invariant): A slot = fq ^ (fr&3); B rows fq*4+j, col e
  const int asw = (fq ^ (fr & 3)) * 8;
  int aoff[4];
  #pragma unroll
  for (int mf = 0; mf < 4; ++mf)
    aoff[mf] = (mw * 64 + mf * 16 + fr) * 32 + asw;
  const int ebase = nw * 32 + fr;

  f32x4 acc[4][2];
  #pragma unroll
  for (int m = 0; m < 4; ++m)
    #pragma unroll
    for (int n = 0; n < 2; ++n)
      #pragma unroll
      for (int j = 0; j < 4; ++j) acc[m][n][j] = 0.f;

  float4 ga[2], gb[2];   // B fp32 register ring, 2 slots (static-indexed)

#define G_LD(S, T) do { \
    ga[S] = *(const float4*)(wsrc0 + (size_t)(T) * 32 * DD); \
    gb[S] = *(const float4*)(wsrc1 + (size_t)(T) * 32 * DD); } while (0)
#define S_A(BF, T) do { \
    gll16(ax0 + (T) * 32, &As[BF][arow][(tid & 3) * 8]); \
    gll16(ax1 + (T) * 32, &As[BF][arow + 64][(tid & 3) * 8]); } while (0)
#define B_ST(BF, S) do { \
    uint4 pv; \
    pv.x = pack2(ga[S].x, gb[S].x); pv.y = pack2(ga[S].y, gb[S].y); \
    pv.z = pack2(ga[S].z, gb[S].z); pv.w = pack2(ga[S].w, gb[S].w); \
    *(uint4*)&Bs[BF][bp * 68 + be] = pv; } while (0)
#define CMP(BF) do { \
    const unsigned int* Bb = Bs[BF]; \
    short8 bf[2]; \
    _Pragma("unroll") for (int n = 0; n < 2; ++n) { \
      uint4 q; \
      q.x = Bb[(fq * 4 + 0) * 68 + ebase + n * 16]; \
      q.y = Bb[(fq * 4 + 1) * 68 + ebase + n * 16]; \
      q.z = Bb[(fq * 4 + 2) * 68 + ebase + n * 16]; \
      q.w = Bb[(fq * 4 + 3) * 68 + ebase + n * 16]; \
      bf[n] = *(short8*)&q; } \
    _Pragma("unroll") for (int mf = 0; mf < 4; ++mf) { \
      short8 af = *(const short8*)((const unsigned short*)As[BF] + aoff[mf]); \
      acc[mf][0] = __builtin_amdgcn_mfma_f32_16x16x32_bf16(af, bf[0], acc[mf][0], 0, 0, 0); \
      acc[mf][1] = __builtin_amdgcn_mfma_f32_16x16x32_bf16(af, bf[1], acc[mf][1], 0, 0, 0); } \
  } while (0)

#define VMW(N) do { asm volatile("s_waitcnt vmcnt(" #N ")" ::: "memory"); \
                    __builtin_amdgcn_sched_barrier(0); } while (0)

// steady iteration: P = t&1. entering: outstanding = {G(t+1):2, S_A(t):2}
#define E_IT(P, T) do { \
    G_LD(P, (T) + 2);                /* +2 -> 6 outstanding */ \
    VMW(2);                          /* retire G(t+1)+S_A(t): A(t) in LDS, B(t+1) in regs */ \
    LGKM0; BARR;                     /* all waves done reading buf P^1; B writes drained */ \
    S_A(P ^ 1, (T) + 1); \
    B_ST(P ^ 1, P ^ 1); \
    CMP(P); \
  } while (0)

  // prologue: G(0)->s0, G(1)->s1, S_A(0)->buf0; wait G(0); B(0)->buf0
  G_LD(0, 0); G_LD(1, 1);
  S_A(0, 0);
  VMW(4);
  B_ST(0, 0);
  // invariant entering t=0: {G(1):2, S_A(0):2}  ✓
  for (int t = 0; t < 30; t += 2) {
    E_IT(0, t);
    E_IT(1, t + 1);
  }
  // tail t=30 (P=0): no G issue; entering {G(31):2, S_A(30):2}
  VMW(0); LGKM0; BARR;
  S_A(1, 31);
  B_ST(1, 1);
  CMP(0);
  // tail t=31 (P=1): entering {S_A(31):2}
  VMW(0); LGKM0; BARR;
  CMP(1);

#undef G_LD
#undef S_A
#undef B_ST
#undef CMP
#undef VMW
#undef E_IT

  // epilogue: D[r][c]: c = lane&15 (e), r = (lane>>4)*4 + j  [m89-verified]
  #pragma unroll
  for (int mf = 0; mf < 4; ++mf) {
    #pragma unroll
    for (int j = 0; j < 4; ++j) {
      const int r = mh * 128 + mw * 64 + mf * 16 + fq * 4 + j;
      if (r < ncnt) {
        const float sc = bscore[l * TT + r];
        float* op = selp + ((size_t)(l * 256 + r) << 10) + n0 + nw * 32 + fr;
        op[0]  = acc[mf][0][j] * sc;
        op[16] = acc[mf][1][j] * sc;
      }
    }
  }
}

// ---------------- combine: lat_bf16[t][d] = sum_k selp[tpos[t*4+k]][d] ----------------
__global__ __launch_bounds__(256) void k_combine(const float* __restrict__ selp,
    const int* __restrict__ tpos, unsigned short* __restrict__ lat)
{
  const size_t i = ((size_t)blockIdx.x * 256 + threadIdx.x) << 2;
  const size_t t = i >> 10, d = i & 1023;
  int4 tp = *(const int4*)(tpos + (t << 2));
  float4 s0 = *(const float4*)(selp + (size_t)tp.x * DD + d);
  float4 s1 = *(const float4*)(selp + (size_t)tp.y * DD + d);
  float4 s2 = *(const float4*)(selp + (size_t)tp.z * DD + d);
  float4 s3 = *(const float4*)(selp + (size_t)tp.w * DD + d);
  float r0 = s0.x + s1.x + s2.x + s3.x;
  float r1 = s0.y + s1.y + s2.y + s3.y;
  float r2 = s0.z + s1.z + s2.z + s3.z;
  float r3 = s0.w + s1.w + s2.w + s3.w;
  uint2 pk; pk.x = pack2(r0, r1); pk.y = pack2(r2, r3);
  *(uint2*)(lat + i) = pk;
}

// ---------------- out_proj: y = x + lat @ out_w^T + b  (BM=128,BN=64, reg-staged dbuf) ----------------
__global__ __launch_bounds__(256, 2) void k_outproj(
    const unsigned short* __restrict__ lat, const float* __restrict__ W2,
    const float* __restrict__ xres, const float* __restrict__ bias,
    float* __restrict__ y)
{
  const int n0 = blockIdx.x * 64;
  const int m0 = blockIdx.y * 128;
  const int tid = threadIdx.x, lane = tid & 63, wid = tid >> 6;

  __shared__ alignas(16) unsigned short As[2][128][40];
  __shared__ alignas(16) unsigned short Bs[2][64][40];

  const int aq = tid >> 2, aseg = tid & 3;
  const unsigned short* la0 = lat + (size_t)(m0 + aq) * DD + aseg * 8;
  const unsigned short* la1 = lat + (size_t)(m0 + aq + 64) * DD + aseg * 8;
  const int be = tid >> 2, bks = tid & 3;
  const float* wb = W2 + (size_t)(n0 + be) * DD + bks * 8;

  f32x4 acc[2][4];
  #pragma unroll
  for (int m = 0; m < 2; ++m)
    #pragma unroll
    for (int n = 0; n < 4; ++n)
      #pragma unroll
      for (int j = 0; j < 4; ++j) acc[m][n][j] = 0.f;

  int4 av0, av1;
  float4 w0, w1;

#define O_LOAD(kk) do { \
    av0 = *(const int4*)(la0 + (kk)); \
    av1 = *(const int4*)(la1 + (kk)); \
    w0 = *(const float4*)(wb + (kk)); \
    w1 = *(const float4*)(wb + (kk) + 4); \
  } while (0)

#define O_STORE(b) do { \
    *(int4*)&As[b][aq][aseg * 8]      = av0; \
    *(int4*)&As[b][aq + 64][aseg * 8] = av1; \
    uint4 pv; \
    pv.x = pack2(w0.x, w0.y); pv.y = pack2(w0.z, w0.w); \
    pv.z = pack2(w1.x, w1.y); pv.w = pack2(w1.z, w1.w); \
    *(uint4*)&Bs[b][be][bks * 8] = pv; \
  } while (0)

  O_LOAD(0); O_STORE(0); __syncthreads();
  int cur = 0;
  for (int t = 0; t < 32; ++t) {
    const bool more = (t < 31);
    if (more) O_LOAD((t + 1) * 32);
    short8 af[2], bf[4];
    #pragma unroll
    for (int n = 0; n < 4; ++n)
      bf[n] = *(const short8*)&Bs[cur][n * 16 + (lane & 15)][(lane >> 4) * 8];
    #pragma unroll
    for (int m = 0; m < 2; ++m)
      af[m] = *(const short8*)&As[cur][wid * 32 + m * 16 + (lane & 15)][(lane >> 4) * 8];
    #pragma unroll
    for (int m = 0; m < 2; ++m)
      #pragma unroll
      for (int n = 0; n < 4; ++n)
        acc[m][n] = __builtin_amdgcn_mfma_f32_16x16x32_bf16(af[m], bf[n], acc[m][n], 0, 0, 0);
    if (more) O_STORE(cur ^ 1);
    __syncthreads();
    cur ^= 1;
  }
#undef O_LOAD
#undef O_STORE

  #pragma unroll
  for (int m = 0; m < 2; ++m) {
    #pragma unroll
    for (int j = 0; j < 4; ++j) {
      const int t = m0 + wid * 32 + m * 16 + ((lane >> 4) << 2) + j;
      #pragma unroll
      for (int n = 0; n < 4; ++n) {
        const int e = n0 + n * 16 + (lane & 15);
        y[(size_t)t * DD + e] = xres[(size_t)t * DD + e] + acc[m][n][j] + bias[e];
      }
    }
  }
}

// ---------------- LayerNorm ----------------
__global__ __launch_bounds__(256) void k_ln(const float* __restrict__ y,
    const float* __restrict__ g, const float* __restrict__ b, float* __restrict__ out)
{
  const int t = blockIdx.x, tid = threadIdx.x;
  float4 v = *(const float4*)(y + (size_t)t * DD + tid * 4);
  float s  = v.x + v.y + v.z + v.w;
  float ss = v.x*v.x + v.y*v.y + v.z*v.z + v.w*v.w;
  #pragma unroll
  for (int off = 32; off; off >>= 1) { s += __shfl_down(s, off); ss += __shfl_down(ss, off); }
  __shared__ float rs[8];
  const int wid = tid >> 6, lane = tid & 63;
  if (lane == 0) { rs[wid] = s; rs[wid + 4] = ss; }
  __syncthreads();
  float S  = rs[0] + rs[1] + rs[2] + rs[3];
  float SS = rs[4] + rs[5] + rs[6] + rs[7];
  float mu = S * (1.0f / DD);
  float var = SS * (1.0f / DD) - mu * mu;
  float inv = rsqrtf(var + 1e-5f);
  float4 gg = *(const float4*)(g + tid * 4);
  float4 bb = *(const float4*)(b + tid * 4);
  float4 o;
  o.x = gg.x * (v.x - mu) * inv + bb.x;
  o.y = gg.y * (v.y - mu) * inv + bb.y;
  o.z = gg.z * (v.z - mu) * inv + bb.z;
  o.w = gg.w * (v.w - mu) * inv + bb.w;
  *(float4*)(out + (size_t)t * DD + tid * 4) = o;
}

extern "C" void kernel_launch(void* const* d_in, const int* in_sizes, int n_in,
                              void* d_out, int out_size, void* d_ws, size_t ws_size,
                              hipStream_t stream) {
  (void)in_sizes; (void)n_in; (void)out_size;
  const float* x   = (const float*)d_in[0];
  const float* gw  = (const float*)d_in[1];
  const float* lw  = (const float*)d_in[2];
  const float* ow  = (const float*)d_in[3];
  const float* obv = (const float*)d_in[4];
  const float* lng = (const float*)d_in[5];
  const float* lnb = (const float*)d_in[6];
  float* out = (float*)d_out;
  char* ws = (char*)d_ws;

  // layout (~87 MB): xg 24MB @0 | selp 48MB+4K @24M | lat @73M | y @77M | counts @85M | bscore | tpos @86M
  unsigned short* xg     = (unsigned short*)(ws);
  float*          selp   = (float*)(ws + (24ull << 20));
  unsigned short* lat    = (unsigned short*)(ws + (73ull << 20));
  float*          y      = (float*)(ws + (77ull << 20));
  int*            counts = (int*)(ws + (85ull << 20));
  float*          bscore = (float*)(ws + (85ull << 20) + 4096);
  int*            tpos   = (int*)(ws + (86ull << 20));
  if (ws_size < (87ull << 20)) return;   // loud failure

  hipMemsetAsync(counts, 0, LL * sizeof(int), stream);
  hipMemsetAsync(selp + (size_t)SENT * DD, 0, DD * sizeof(float), stream);  // sentinel row
  k_gate<<<TT / 8, 256, 0, stream>>>(x, gw, xg, counts, bscore, tpos);
  k_expert<<<1536, 256, 0, stream>>>(xg, lw, counts, bscore, selp);
  k_combine<<<TT * DD / (256 * 4), 256, 0, stream>>>(selp, tpos, lat);
  k_outproj<<<dim3(16, 16), 256, 0, stream>>>(lat, ow, x, obv, y);
  k_ln<<<TT, 256, 0, stream>>>(y, lng, lnb, out);
}